// Round 7
// baseline (1657.448 us; speedup 1.0000x reference)
//
#include <hip/hip_runtime.h>
#include <hip/hip_fp16.h>
#include <math.h>

#define R2 2500.0f
#define EPSF 1e-8f

constexpr int H  = 256;    // feature dim
constexpr int HH = 128;    // hidden dim
constexpr int NN = 16384;
constexpr int EE = 524288;

// fvar SpMM geometry
constexpr int SLICE_COLS = 256;               // cols per staged slice (128KB fp16)
constexpr int NPASS = NN / SLICE_COLS;        // 64
constexpr int ROWS_WG = 64;                   // 8 waves x 8 rows
constexpr int NWG = NN / ROWS_WG;             // 256
constexpr int NRG = NN / 8;                   // 2048 rowgroups
constexpr int NB2 = NRG * NPASS;              // 131072 buckets
constexpr int MAXE_W = 512;                   // max edges per rowgroup (Poisson(256), 16 sigma)

// ---------------- K1: degree + bucket count (merged) ----------------
__global__ void k_prep(const int* __restrict__ row, const int* __restrict__ col,
                       int* __restrict__ deg, int* __restrict__ bcnt, int E) {
    int e = blockIdx.x * blockDim.x + threadIdx.x;
    if (e < E) {
        int r = row[e], c = col[e];
        atomicAdd(&deg[r], 1);
        atomicAdd(&bcnt[(r >> 3) * NPASS + (c >> 8)], 1);
    }
}

// ---------------- K2: exclusive scan over 131072 buckets (1 block) -----------
__global__ void k_bscan(const int* __restrict__ bcnt, int* __restrict__ bptr, int total) {
    __shared__ int s[1024];
    int t = threadIdx.x;
    int per = total >> 10;           // 128
    int base = t * per;
    int local = 0;
    for (int k = 0; k < per; k++) local += bcnt[base + k];
    s[t] = local;
    __syncthreads();
    for (int off = 1; off < 1024; off <<= 1) {
        int v = s[t];
        int add = (t >= off) ? s[t - off] : 0;
        __syncthreads();
        s[t] = v + add;
        __syncthreads();
    }
    int excl = (t > 0) ? s[t - 1] : 0;
    for (int k = 0; k < per; k++) {
        int v = bcnt[base + k];
        bptr[base + k] = excl;
        excl += v;
    }
    if (t == 1023) bptr[total] = excl;
}

// ---------------- K3: bucket fill (u32: row_local<<14 | col) ----------------
__global__ void k_bfill(const int* __restrict__ row, const int* __restrict__ col,
                        const int* __restrict__ bptr, int* __restrict__ bfill,
                        unsigned int* __restrict__ bedge, int E) {
    int e = blockIdx.x * blockDim.x + threadIdx.x;
    if (e < E) {
        int r = row[e], c = col[e];
        int b = (r >> 3) * NPASS + (c >> 8);
        int p = bptr[b] + atomicAdd(&bfill[b], 1);
        bedge[p] = ((unsigned int)(r & 7) << 14) | (unsigned int)c;
    }
}

// ---------------- K4: x -> fp16 copy ----------------
__global__ void k_half(const float* __restrict__ x, unsigned short* __restrict__ xh,
                       int total4) {
    int t = blockIdx.x * blockDim.x + threadIdx.x;
    if (t < total4) {
        float4 v = ((const float4*)x)[t];
        __half2 a = __floats2half2_rn(v.x, v.y);
        __half2 b = __floats2half2_rn(v.z, v.w);
        uint2 r;
        r.x = __builtin_bit_cast(unsigned int, a);
        r.y = __builtin_bit_cast(unsigned int, b);
        ((uint2*)xh)[t] = r;
    }
}

// ---------------- K5: spatial density (pairwise count) ----------------
__global__ void k_density(const float* __restrict__ coords, int* __restrict__ dens,
                          int N, int jPer) {
    __shared__ float sx[256], sy[256], sq[256];
    int i = blockIdx.x * 256 + threadIdx.x;
    const float2* c2 = (const float2*)coords;
    float2 ci = c2[i];
    float sqi = ci.x * ci.x + ci.y * ci.y;
    int j0 = blockIdx.y * jPer;
    int cnt = 0;
    for (int jt = j0; jt < j0 + jPer; jt += 256) {
        float2 cj = c2[jt + threadIdx.x];
        sx[threadIdx.x] = cj.x;
        sy[threadIdx.x] = cj.y;
        sq[threadIdx.x] = cj.x * cj.x + cj.y * cj.y;
        __syncthreads();
#pragma unroll 8
        for (int k = 0; k < 256; k++) {
            float dot = ci.x * sx[k] + ci.y * sy[k];
            float d2 = (sqi + sq[k]) - 2.0f * dot;
            cnt += (d2 <= R2) ? 1 : 0;
        }
        __syncthreads();
    }
    atomicAdd(&dens[i], cnt);
}

// ---------------- K6: fvar streaming SpMM ----------------
// Wave owns 8 rows; acc = 8 x float4 in VGPRs (no atomics). 64 passes stage
// 256-col fp16 X slices into LDS (coalesced, reg-prefetched one pass ahead).
// __launch_bounds__(512,2): 144KB dynamic LDS already limits to 1 block/CU
// (2 waves/EU); without this the compiler targets 8 waves/EU, caps VGPR at 64,
// and spills pf[16]+accumulators to scratch (R5: 2.1GB scratch writes).
__global__ void __launch_bounds__(512, 2) k_fvarS(
    const float* __restrict__ x, const unsigned short* __restrict__ xh,
    const int* __restrict__ bptr, const unsigned int* __restrict__ bedge,
    const int* __restrict__ deg, const int* __restrict__ dens,
    float* __restrict__ fvar, int* __restrict__ scal) {
    extern __shared__ char smem[];
    uint2* slice = (uint2*)smem;                                   // 256 cols * 512B = 128KB
    unsigned int* ledges = (unsigned int*)(smem + SLICE_COLS * 512); // 8 waves * 512 * 4B = 16KB
    int t = threadIdx.x;
    int wave = t >> 6, lane = t & 63;
    int rg = blockIdx.x * 8 + wave;            // rowgroup: rows rg*8 .. rg*8+7

    int s = bptr[rg * NPASS];
    int cnt = bptr[rg * NPASS + NPASS] - s;
    if (cnt > MAXE_W) cnt = MAXE_W;
    for (int k = lane; k < cnt; k += 64) ledges[wave * MAXE_W + k] = bedge[s + k];

    const uint4* xh4 = (const uint4*)xh;       // one pass slice = 8192 uint4
    uint4 pf[16];
#pragma unroll
    for (int k = 0; k < 16; k++) pf[k] = xh4[t + k * 512];

    float4 a0 = {0,0,0,0}, a1 = {0,0,0,0}, a2 = {0,0,0,0}, a3 = {0,0,0,0};
    float4 a4 = {0,0,0,0}, a5 = {0,0,0,0}, a6 = {0,0,0,0}, a7 = {0,0,0,0};
    int j = 0;
    __syncthreads();   // ledges visible

    for (int p = 0; p < NPASS; p++) {
        uint4* sl4 = (uint4*)slice;
#pragma unroll
        for (int k = 0; k < 16; k++) sl4[t + k * 512] = pf[k];
        if (p + 1 < NPASS) {
            const uint4* src = xh4 + (size_t)(p + 1) * 8192;
#pragma unroll
            for (int k = 0; k < 16; k++) pf[k] = src[t + k * 512];
        }
        __syncthreads();   // slice ready
        while (j < cnt) {
            unsigned int pk = ledges[wave * MAXE_W + j];   // broadcast (uniform)
            if (((pk >> 8) & 63u) != (unsigned int)p) break;
            int cl = pk & 255;
            uint2 hv = slice[cl * 64 + lane];
            __half2 h0 = __builtin_bit_cast(__half2, hv.x);
            __half2 h1 = __builtin_bit_cast(__half2, hv.y);
            float2 f0 = __half22float2(h0);
            float2 f1 = __half22float2(h1);
            switch (pk >> 14) {    // wave-uniform branch
                case 0: a0.x += f0.x; a0.y += f0.y; a0.z += f1.x; a0.w += f1.y; break;
                case 1: a1.x += f0.x; a1.y += f0.y; a1.z += f1.x; a1.w += f1.y; break;
                case 2: a2.x += f0.x; a2.y += f0.y; a2.z += f1.x; a2.w += f1.y; break;
                case 3: a3.x += f0.x; a3.y += f0.y; a3.z += f1.x; a3.w += f1.y; break;
                case 4: a4.x += f0.x; a4.y += f0.y; a4.z += f1.x; a4.w += f1.y; break;
                case 5: a5.x += f0.x; a5.y += f0.y; a5.z += f1.x; a5.w += f1.y; break;
                case 6: a6.x += f0.x; a6.y += f0.y; a6.z += f1.x; a6.w += f1.y; break;
                default: a7.x += f0.x; a7.y += f0.y; a7.z += f1.x; a7.w += f1.y; break;
            }
            j++;
        }
        __syncthreads();   // edges done before slice overwrite
    }

    float4 accs[8] = {a0, a1, a2, a3, a4, a5, a6, a7};
#pragma unroll
    for (int n = 0; n < 8; n++) {
        int i = rg * 8 + n;
        int dg = deg[i];
        float cntf = fmaxf((float)dg, 1.0f);
        float4 xi = ((const float4*)x)[(size_t)i * 64 + lane];
        float dx = xi.x - accs[n].x / cntf;
        float dy = xi.y - accs[n].y / cntf;
        float dz = xi.z - accs[n].z / cntf;
        float dw = xi.w - accs[n].w / cntf;
        float ss = dx * dx + dy * dy + dz * dz + dw * dw;
#pragma unroll
        for (int off = 32; off > 0; off >>= 1) ss += __shfl_xor(ss, off, 64);
        if (lane == 0) {
            float fv = sqrtf(ss);
            fvar[i] = fv;
            atomicMax(&scal[0], dg);
            atomicMax(&scal[1], dens[i]);
            atomicMax(&scal[2], __float_as_int(fv));
        }
    }
}

// ---------------- K7: tiny MLP ----------------
__global__ void __launch_bounds__(256) k_mlp(
    const float* __restrict__ w1, const float* __restrict__ b1,
    const float* __restrict__ w2, const float* __restrict__ b2,
    const int* __restrict__ deg, const int* __restrict__ dens,
    const float* __restrict__ fvar, const int* __restrict__ scal,
    float* __restrict__ out, int N) {
    __shared__ float sh_h[HH];
    int j = threadIdx.x;
    float wv[HH];
#pragma unroll
    for (int l = 0; l < HH; l++) wv[l] = w2[l * H + j];
    float bj = b2[j];
    float maxdeg  = (float)scal[0] + EPSF;
    float maxdens = (float)(scal[1] - 1) + EPSF;
    float maxfv   = __int_as_float(scal[2]) + EPSF;
    float w1a = 0.f, w1b = 0.f, w1c = 0.f, b1j = 0.f;
    if (j < HH) { w1a = w1[j]; w1b = w1[HH + j]; w1c = w1[2 * HH + j]; b1j = b1[j]; }
    for (int i = blockIdx.x; i < N; i += gridDim.x) {
        float f0 = (float)deg[i] / maxdeg;
        float f1 = (float)(dens[i] - 1) / maxdens;
        float f2 = fvar[i] / maxfv;
        if (j < HH) {
            float h = f0 * w1a + f1 * w1b + f2 * w1c + b1j;
            sh_h[j] = fmaxf(h, 0.0f);
        }
        __syncthreads();
        float acc = bj;
#pragma unroll
        for (int l = 0; l < HH; l++) acc = fmaf(sh_h[l], wv[l], acc);
        out[(size_t)i * H + j] = acc;
        __syncthreads();
    }
}

extern "C" void kernel_launch(void* const* d_in, const int* in_sizes, int n_in,
                              void* d_out, int out_size, void* d_ws, size_t ws_size,
                              hipStream_t stream) {
    const float* x      = (const float*)d_in[0];
    const int*   ei     = (const int*)d_in[1];
    const float* coords = (const float*)d_in[2];
    const float* w1     = (const float*)d_in[3];
    const float* b1     = (const float*)d_in[4];
    const float* w2     = (const float*)d_in[5];
    const float* b2     = (const float*)d_in[6];
    float* out = (float*)d_out;

    const int N = in_sizes[2] / 2;   // 16384
    const int E = in_sizes[1] / 2;   // 524288
    const int* row = ei;
    const int* col = ei + E;

    // workspace layout (int32 elements) — ~11.7MB total
    int* ws       = (int*)d_ws;
    int* deg_cnt  = ws;                          // [N]       zeroed
    int* dens_cnt = ws + N;                      // [N]       zeroed
    int* scal     = ws + 2 * N;                  // [4]       zeroed
    int* bcnt     = ws + 2 * N + 4;              // [NB2]     zeroed (reused as bfill)
    int* bptr     = bcnt + NB2;                  // [NB2+4]
    float* fvarp  = (float*)(bptr + NB2 + 4);    // [N]
    unsigned int* bedge = (unsigned int*)(fvarp + N);          // [E] u32
    unsigned short* xh  = (unsigned short*)(bedge + E);        // [N*H] fp16 (16B aligned)

    hipMemsetAsync(ws, 0, (size_t)(2 * N + 4 + NB2) * sizeof(int), stream);

    int eb = (E + 255) / 256;
    k_prep<<<eb, 256, 0, stream>>>(row, col, deg_cnt, bcnt, E);
    k_bscan<<<1, 1024, 0, stream>>>(bcnt, bptr, NB2);
    hipMemsetAsync(bcnt, 0, (size_t)NB2 * sizeof(int), stream);   // reuse as bfill
    k_bfill<<<eb, 256, 0, stream>>>(row, col, bptr, bcnt, bedge, E);

    int t4 = N * (H / 4);
    k_half<<<(t4 + 255) / 256, 256, 0, stream>>>(x, xh, t4);

    const int NSLICE = 8;
    k_density<<<dim3(N / 256, NSLICE), 256, 0, stream>>>(coords, dens_cnt, N, N / NSLICE);

    hipFuncSetAttribute((const void*)k_fvarS,
                        hipFuncAttributeMaxDynamicSharedMemorySize, 147456);
    k_fvarS<<<NWG, 512, 147456, stream>>>(x, xh, bptr, bedge, deg_cnt, dens_cnt,
                                          fvarp, scal);

    k_mlp<<<1024, 256, 0, stream>>>(w1, b1, w2, b2, deg_cnt, dens_cnt, fvarp, scal,
                                    out, N);
}

// Round 8
// 1099.100 us; speedup vs baseline: 1.5080x; 1.5080x over previous
//
#include <hip/hip_runtime.h>
#include <hip/hip_fp16.h>
#include <math.h>

#define R2 2500.0f
#define EPSF 1e-8f

constexpr int H  = 256;    // feature dim
constexpr int HH = 128;    // hidden dim
constexpr int NN = 16384;
constexpr int EE = 524288;

// fvar SpMM geometry
constexpr int SLICE_COLS = 256;               // cols per staged slice (128KB fp16)
constexpr int NPASS = NN / SLICE_COLS;        // 64
constexpr int ROWS_WG = 64;                   // 8 waves x 8 rows
constexpr int NWG = NN / ROWS_WG;             // 256
constexpr int NRG = NN / 8;                   // 2048 rowgroups
constexpr int NB2 = NRG * NPASS;              // 131072 buckets
constexpr int MAXE_W = 512;                   // max edges per rowgroup (Poisson(256), 16 sigma)

// ---------------- K1: degree + bucket count (merged) ----------------
__global__ void k_prep(const int* __restrict__ row, const int* __restrict__ col,
                       int* __restrict__ deg, int* __restrict__ bcnt, int E) {
    int e = blockIdx.x * blockDim.x + threadIdx.x;
    if (e < E) {
        int r = row[e], c = col[e];
        atomicAdd(&deg[r], 1);
        atomicAdd(&bcnt[(r >> 3) * NPASS + (c >> 8)], 1);
    }
}

// ---------------- K2: exclusive scan over 131072 buckets (1 block, int4) -----
__global__ void k_bscan(const int* __restrict__ bcnt, int* __restrict__ bptr, int total) {
    __shared__ int s[1024];
    int t = threadIdx.x;
    int per4 = total >> 12;          // int4s per thread = 32
    const int4* b4 = (const int4*)bcnt;
    int4* p4 = (int4*)bptr;
    int base = t * per4;
    int local = 0;
    for (int k = 0; k < per4; k++) {
        int4 v = b4[base + k];
        local += v.x + v.y + v.z + v.w;
    }
    s[t] = local;
    __syncthreads();
    for (int off = 1; off < 1024; off <<= 1) {
        int v = s[t];
        int add = (t >= off) ? s[t - off] : 0;
        __syncthreads();
        s[t] = v + add;
        __syncthreads();
    }
    int excl = (t > 0) ? s[t - 1] : 0;
    for (int k = 0; k < per4; k++) {
        int4 v = b4[base + k];
        int4 w;
        w.x = excl;
        w.y = w.x + v.x;
        w.z = w.y + v.y;
        w.w = w.z + v.z;
        excl = w.w + v.w;
        p4[base + k] = w;
    }
    if (t == 1023) bptr[total] = excl;
}

// ---------------- K3: bucket fill (u32: row_local<<14 | col) ----------------
__global__ void k_bfill(const int* __restrict__ row, const int* __restrict__ col,
                        const int* __restrict__ bptr, int* __restrict__ bfill,
                        unsigned int* __restrict__ bedge, int E) {
    int e = blockIdx.x * blockDim.x + threadIdx.x;
    if (e < E) {
        int r = row[e], c = col[e];
        int b = (r >> 3) * NPASS + (c >> 8);
        int p = bptr[b] + atomicAdd(&bfill[b], 1);
        bedge[p] = ((unsigned int)(r & 7) << 14) | (unsigned int)c;
    }
}

// ---------------- K4: x -> fp16 copy ----------------
__global__ void k_half(const float* __restrict__ x, unsigned short* __restrict__ xh,
                       int total4) {
    int t = blockIdx.x * blockDim.x + threadIdx.x;
    if (t < total4) {
        float4 v = ((const float4*)x)[t];
        __half2 a = __floats2half2_rn(v.x, v.y);
        __half2 b = __floats2half2_rn(v.z, v.w);
        uint2 r;
        r.x = __builtin_bit_cast(unsigned int, a);
        r.y = __builtin_bit_cast(unsigned int, b);
        ((uint2*)xh)[t] = r;
    }
}

// ---------------- K5: spatial density (pairwise count) ----------------
__global__ void k_density(const float* __restrict__ coords, int* __restrict__ dens,
                          int N, int jPer) {
    __shared__ float sx[256], sy[256], sq[256];
    int i = blockIdx.x * 256 + threadIdx.x;
    const float2* c2 = (const float2*)coords;
    float2 ci = c2[i];
    float sqi = ci.x * ci.x + ci.y * ci.y;
    int j0 = blockIdx.y * jPer;
    int cnt = 0;
    for (int jt = j0; jt < j0 + jPer; jt += 256) {
        float2 cj = c2[jt + threadIdx.x];
        sx[threadIdx.x] = cj.x;
        sy[threadIdx.x] = cj.y;
        sq[threadIdx.x] = cj.x * cj.x + cj.y * cj.y;
        __syncthreads();
#pragma unroll 8
        for (int k = 0; k < 256; k++) {
            float dot = ci.x * sx[k] + ci.y * sy[k];
            float d2 = (sqi + sq[k]) - 2.0f * dot;
            cnt += (d2 <= R2) ? 1 : 0;
        }
        __syncthreads();
    }
    atomicAdd(&dens[i], cnt);
}

// ---------------- K6: fvar streaming SpMM (DMA staging, reg edges) ----------
// Wave owns 8 rows (8 float4 acc in VGPRs). 64 passes; each stages a 128KB
// contiguous fp16 X col-slice via global_load_lds DMA (zero VGPR cost), then
// consumes this wave's bucket-sorted edges for that col-range from 8 per-lane
// edge registers (uniform switch + shfl broadcast). Pressure ~55 VGPR -> no
// spill at the compiler's default 8-wave/64-VGPR target (R5/R6 failure mode).
__global__ void __launch_bounds__(512) k_fvar(
    const float* __restrict__ x, const unsigned short* __restrict__ xh,
    const int* __restrict__ bptr, const unsigned int* __restrict__ bedge,
    const int* __restrict__ deg, const int* __restrict__ dens,
    float* __restrict__ fvar, int* __restrict__ scal, int E) {
    extern __shared__ char smem[];                 // 128KB slice
    const uint2* slice_u2 = (const uint2*)smem;
    int t = threadIdx.x;
    int wave = t >> 6, lane = t & 63;
    int rg = blockIdx.x * 8 + wave;                // rows rg*8 .. rg*8+7

    int s = bptr[rg * NPASS];
    int cnt = bptr[rg * NPASS + NPASS] - s;
    if (cnt > MAXE_W) cnt = MAXE_W;
    // preload this wave's edges into 8 per-lane registers
    unsigned int ev0, ev1, ev2, ev3, ev4, ev5, ev6, ev7;
    {
        int last = E - 1;
        auto ld = [&](int k) {
            int idx = s + k * 64 + lane;
            return bedge[idx < last ? idx : last];
        };
        ev0 = ld(0); ev1 = ld(1); ev2 = ld(2); ev3 = ld(3);
        ev4 = ld(4); ev5 = ld(5); ev6 = ld(6); ev7 = ld(7);
    }

    float4 a0 = {0,0,0,0}, a1 = {0,0,0,0}, a2 = {0,0,0,0}, a3 = {0,0,0,0};
    float4 a4 = {0,0,0,0}, a5 = {0,0,0,0}, a6 = {0,0,0,0}, a7 = {0,0,0,0};
    int j = 0;

    const uint4* xh4 = (const uint4*)xh;           // slice p = 8192 uint4

    for (int p = 0; p < NPASS; p++) {
        // stage slice p: wave handles 16 x 1KB chunks
        {
            const uint4* src = xh4 + (size_t)p * 8192 + (wave * 16) * 64 + lane;
            char* dst = smem + (size_t)(wave * 16) * 1024;
#pragma unroll
            for (int k = 0; k < 16; k++) {
                __builtin_amdgcn_global_load_lds(
                    (const __attribute__((address_space(1))) void*)(src + k * 64),
                    (__attribute__((address_space(3))) void*)(dst + k * 1024),
                    16, 0, 0);
            }
        }
        __builtin_amdgcn_s_waitcnt(0);
        __syncthreads();                           // slice visible to all waves
        while (j < cnt) {
            unsigned int pk;
            switch (j >> 6) {                      // wave-uniform
                case 0: pk = __shfl(ev0, j & 63, 64); break;
                case 1: pk = __shfl(ev1, j & 63, 64); break;
                case 2: pk = __shfl(ev2, j & 63, 64); break;
                case 3: pk = __shfl(ev3, j & 63, 64); break;
                case 4: pk = __shfl(ev4, j & 63, 64); break;
                case 5: pk = __shfl(ev5, j & 63, 64); break;
                case 6: pk = __shfl(ev6, j & 63, 64); break;
                default: pk = __shfl(ev7, j & 63, 64); break;
            }
            if (((pk >> 8) & 63u) != (unsigned int)p) break;
            int cl = pk & 255;
            uint2 hv = slice_u2[cl * 64 + lane];
            __half2 h0 = __builtin_bit_cast(__half2, hv.x);
            __half2 h1 = __builtin_bit_cast(__half2, hv.y);
            float2 f0 = __half22float2(h0);
            float2 f1 = __half22float2(h1);
            switch (pk >> 14) {                    // wave-uniform
                case 0: a0.x += f0.x; a0.y += f0.y; a0.z += f1.x; a0.w += f1.y; break;
                case 1: a1.x += f0.x; a1.y += f0.y; a1.z += f1.x; a1.w += f1.y; break;
                case 2: a2.x += f0.x; a2.y += f0.y; a2.z += f1.x; a2.w += f1.y; break;
                case 3: a3.x += f0.x; a3.y += f0.y; a3.z += f1.x; a3.w += f1.y; break;
                case 4: a4.x += f0.x; a4.y += f0.y; a4.z += f1.x; a4.w += f1.y; break;
                case 5: a5.x += f0.x; a5.y += f0.y; a5.z += f1.x; a5.w += f1.y; break;
                case 6: a6.x += f0.x; a6.y += f0.y; a6.z += f1.x; a6.w += f1.y; break;
                default: a7.x += f0.x; a7.y += f0.y; a7.z += f1.x; a7.w += f1.y; break;
            }
            j++;
        }
        __syncthreads();                           // all reads done before overwrite
    }

    float4 accs[8] = {a0, a1, a2, a3, a4, a5, a6, a7};
#pragma unroll
    for (int n = 0; n < 8; n++) {
        int i = rg * 8 + n;
        int dg = deg[i];
        float cntf = fmaxf((float)dg, 1.0f);
        float4 xi = ((const float4*)x)[(size_t)i * 64 + lane];
        float dx = xi.x - accs[n].x / cntf;
        float dy = xi.y - accs[n].y / cntf;
        float dz = xi.z - accs[n].z / cntf;
        float dw = xi.w - accs[n].w / cntf;
        float ss = dx * dx + dy * dy + dz * dz + dw * dw;
#pragma unroll
        for (int off = 32; off > 0; off >>= 1) ss += __shfl_xor(ss, off, 64);
        if (lane == 0) {
            float fv = sqrtf(ss);
            fvar[i] = fv;
            atomicMax(&scal[0], dg);
            atomicMax(&scal[1], dens[i]);
            atomicMax(&scal[2], __float_as_int(fv));
        }
    }
}

// ---------------- K7: tiny MLP ----------------
__global__ void __launch_bounds__(256) k_mlp(
    const float* __restrict__ w1, const float* __restrict__ b1,
    const float* __restrict__ w2, const float* __restrict__ b2,
    const int* __restrict__ deg, const int* __restrict__ dens,
    const float* __restrict__ fvar, const int* __restrict__ scal,
    float* __restrict__ out, int N) {
    __shared__ float sh_h[HH];
    int j = threadIdx.x;
    float wv[HH];
#pragma unroll
    for (int l = 0; l < HH; l++) wv[l] = w2[l * H + j];
    float bj = b2[j];
    float maxdeg  = (float)scal[0] + EPSF;
    float maxdens = (float)(scal[1] - 1) + EPSF;
    float maxfv   = __int_as_float(scal[2]) + EPSF;
    float w1a = 0.f, w1b = 0.f, w1c = 0.f, b1j = 0.f;
    if (j < HH) { w1a = w1[j]; w1b = w1[HH + j]; w1c = w1[2 * HH + j]; b1j = b1[j]; }
    for (int i = blockIdx.x; i < N; i += gridDim.x) {
        float f0 = (float)deg[i] / maxdeg;
        float f1 = (float)(dens[i] - 1) / maxdens;
        float f2 = fvar[i] / maxfv;
        if (j < HH) {
            float h = f0 * w1a + f1 * w1b + f2 * w1c + b1j;
            sh_h[j] = fmaxf(h, 0.0f);
        }
        __syncthreads();
        float acc = bj;
#pragma unroll
        for (int l = 0; l < HH; l++) acc = fmaf(sh_h[l], wv[l], acc);
        out[(size_t)i * H + j] = acc;
        __syncthreads();
    }
}

extern "C" void kernel_launch(void* const* d_in, const int* in_sizes, int n_in,
                              void* d_out, int out_size, void* d_ws, size_t ws_size,
                              hipStream_t stream) {
    const float* x      = (const float*)d_in[0];
    const int*   ei     = (const int*)d_in[1];
    const float* coords = (const float*)d_in[2];
    const float* w1     = (const float*)d_in[3];
    const float* b1     = (const float*)d_in[4];
    const float* w2     = (const float*)d_in[5];
    const float* b2     = (const float*)d_in[6];
    float* out = (float*)d_out;

    const int N = in_sizes[2] / 2;   // 16384
    const int E = in_sizes[1] / 2;   // 524288
    const int* row = ei;
    const int* col = ei + E;

    // workspace layout (int32 elements) — ~9.6MB total
    int* ws       = (int*)d_ws;
    int* deg_cnt  = ws;                          // [N]       zeroed
    int* dens_cnt = ws + N;                      // [N]       zeroed
    int* scal     = ws + 2 * N;                  // [4]       zeroed
    int* bcnt     = ws + 2 * N + 4;              // [NB2]     zeroed (reused as bfill)
    int* bptr     = bcnt + NB2;                  // [NB2+4]
    float* fvarp  = (float*)(bptr + NB2 + 4);    // [N]
    unsigned int* bedge = (unsigned int*)(fvarp + N);          // [E] u32
    unsigned short* xh  = (unsigned short*)(bedge + E);        // [N*H] fp16 (16B aligned)

    hipMemsetAsync(ws, 0, (size_t)(2 * N + 4 + NB2) * sizeof(int), stream);

    int eb = (E + 255) / 256;
    k_prep<<<eb, 256, 0, stream>>>(row, col, deg_cnt, bcnt, E);
    k_bscan<<<1, 1024, 0, stream>>>(bcnt, bptr, NB2);
    hipMemsetAsync(bcnt, 0, (size_t)NB2 * sizeof(int), stream);   // reuse as bfill
    k_bfill<<<eb, 256, 0, stream>>>(row, col, bptr, bcnt, bedge, E);

    int t4 = N * (H / 4);
    k_half<<<(t4 + 255) / 256, 256, 0, stream>>>(x, xh, t4);

    const int NSLICE = 8;
    k_density<<<dim3(N / 256, NSLICE), 256, 0, stream>>>(coords, dens_cnt, N, N / NSLICE);

    hipFuncSetAttribute((const void*)k_fvar,
                        hipFuncAttributeMaxDynamicSharedMemorySize, 131072);
    k_fvar<<<NWG, 512, 131072, stream>>>(x, xh, bptr, bedge, deg_cnt, dens_cnt,
                                         fvarp, scal, E);

    k_mlp<<<1024, 256, 0, stream>>>(w1, b1, w2, b2, deg_cnt, dens_cnt, fvarp, scal,
                                    out, N);
}